// Round 14
// baseline (37.696 us; speedup 1.0000x reference)
//
#include <hip/hip_runtime.h>

#define DTF (1.0f/120.0f)

constexpr int Bn = 2048, Tn = 2048, NS = Tn - 1, ZF = Tn * 3;
constexpr int NSUP = 16;              // time superblocks
constexpr int BT = 128;               // 2 waves; 64 trajectories per block
constexpr int NG = Bn / 64;           // 32 trajectory groups
constexpr int NBLK = NG * NSUP;       // 512
constexpr int SLOT_F = 64 * 96;       // 24 KB frame slot (32 steps x 64 rows)

// ---- main: shared 192-step window, 2 waves, full-line gload_lds, xor-swizzled LDS ----
__global__ __launch_bounds__(BT, 2) void ekf_main(const float* __restrict__ params,
                                                  const float* __restrict__ meas,
                                                  double* __restrict__ part)
{
    __shared__ __align__(16) float lds[3 * SLOT_F];   // 72 KB ring
    __shared__ double wsum[2];

    const int tid = threadIdx.x, wid = tid >> 6, lane = tid & 63;
    const int B = blockIdx.x;
    const int g = (B & 7) + 8 * ((B >> 3) >> 4);      // group co-located per XCD
    const int S = (B >> 3) & 15;                      // superblock
    const int jz = 128 * S;                           // window z-start (≡0 mod 32)
    const int T_S = (S == 15) ? 4 : 6;                // frames this block

    const float dt = DTF, fric = params[0], damping = params[1];
    const float a = 1.f - dt * damping, dfr = dt * fric;
    const float dt2 = dt * dt, a2 = a * a;
    const float qp = 2e-10f, qv = 3e-7f, qth = 1e-2f, qdth = 1e-1f;
    const float Rp = 2.5e-7f, Rt = 9.1e-3f;
    const char* __restrict__ zb = (const char*)(meas + (size_t)g * 64 * ZF);

    const bool exact = (S == 0 && wid == 0);
    const int mst   = (S == 0 && wid == 1) ? 33 : (1 + 64 * wid);      // first consumed m
    const int mown0 = (S == 0) ? (wid ? 96 : 1) : (64 * (wid + 1));    // owned [mown0,mown1)
    const int mown1 = min((S == 0) ? (wid ? 192 : 96) : (64 * (wid + 2)), 2048 - jz);

    // staging map: instr (12*wid+i), lane -> LDS chunk C; source chunk xor-swizzled in-row
    int rbyte[12];
    #pragma unroll
    for (int i = 0; i < 12; ++i) {
        int ig = 12 * wid + i, C = 64 * ig + lane;
        int r = C / 24, c = C - 24 * r;
        rbyte[i] = r * (ZF * 4) + ((c ^ (r & 7)) * 16);
    }

#define ISSUE(F) do { \
    int foff_ = (3 * jz + 96 * (F)) * 4; \
    float* db_ = &lds[((F) % 3) * SLOT_F + wid * 12 * 256]; \
    _Pragma("unroll") \
    for (int i_ = 0; i_ < 12; ++i_) \
        __builtin_amdgcn_global_load_lds((const void*)(zb + rbyte[i_] + foff_), \
                                         (void*)(db_ + i_ * 256), 16, 0, 0); \
} while (0)

    ISSUE(0); ISSUE(1); ISSUE(2);

    // converged gains (tail waves) under the prologue loads
    float ckx0, ckx1, ckt0, ckt1, cisx, cist, cdet;
    {
        float x00=0.01f, x01=0.f, x11=0.01f, t00=0.01f, t01=0.f, t11=0.01f;
        for (int t = 0; t < 48; ++t) {
            float Pp00 = fmaf(dt2, x11, fmaf(2.f*dt, x01, x00)) + qp;
            float Pp01 = a * fmaf(dt, x11, x01);
            float Pp11 = fmaf(a2, x11, qv);
            float Sx = Pp00 + Rp, isx = __builtin_amdgcn_rcpf(Sx);
            float kx0 = Pp00*isx, kx1 = Pp01*isx;
            x00 = Pp00-kx0*Pp00; x01 = Pp01-kx0*Pp01; x11 = Pp11-kx1*Pp01;
            float Tp00 = fmaf(dt2, t11, fmaf(2.f*dt, t01, t00)) + qth;
            float Tp01 = fmaf(dt, t11, t01);
            float Tp11 = t11 + qdth;
            float St = Tp00 + Rt, ist = __builtin_amdgcn_rcpf(St);
            float kt0 = Tp00*ist, kt1 = Tp01*ist;
            t00 = Tp00-kt0*Tp00; t01 = Tp01-kt0*Tp01; t11 = Tp11-kt1*Tp01;
            ckx0=kx0; ckx1=kx1; ckt0=kt0; ckt1=kt1; cisx=isx; cist=ist; cdet=Sx*Sx*St;
        }
    }

    float s0=0.f,s1=0.f,s2=0.f,s3=0.f,s4=0.f,s5=0.f;
    float hx00=0.01f,hx01=0.f,hx11=0.01f,ht00=0.01f,ht01=0.f,ht11=0.01f;
    float facc=0.f, accP=0.f, accT=0.f;
    int nown = 0;
    bool inited = false;
    const int rx = lane & 7;

#define PRED_UPD(KX0,KX1,KT0,KT1,Z0,Z1,Z2) \
    float p0=fmaf(dt,s2,s0), p1=fmaf(dt,s3,s1), p4=fmaf(dt,s5,s4); \
    float p2=fmaf(a,s2,-copysignf(dfr,s2)), p3=fmaf(a,s3,-copysignf(dfr,s3)); \
    float y0=(Z0)-p0, y1=(Z1)-p1, y2=(Z2)-p4; \
    s0=fmaf(KX0,y0,p0); s1=fmaf(KX0,y1,p1); s2=fmaf(KX1,y0,p2); s3=fmaf(KX1,y1,p3); \
    s4=fmaf(KT0,y2,p4); s5=fmaf(KT1,y2,s5);

#define TSTEP(K,Z0,Z1,Z2) { int m=m0+(K); if (m>=mst && m<mown1) { \
    PRED_UPD(ckx0,ckx1,ckt0,ckt1,Z0,Z1,Z2) \
    if (m>=mown0) { accP=fmaf(y0,y0,fmaf(y1,y1,accP)); accT=fmaf(y2,y2,accT); ++nown; } } }

#define XSTEP(K,Z0,Z1,Z2) { int m=m0+(K); if (m>=mst && m<mown1) { \
    float Pp00=fmaf(dt2,hx11,fmaf(2.f*dt,hx01,hx00))+qp; \
    float Pp01=a*fmaf(dt,hx11,hx01); \
    float Pp11=fmaf(a2,hx11,qv); \
    float Sx=Pp00+Rp, isx=__builtin_amdgcn_rcpf(Sx); \
    float kx0=Pp00*isx, kx1=Pp01*isx; \
    hx00=Pp00-kx0*Pp00; hx01=Pp01-kx0*Pp01; hx11=Pp11-kx1*Pp01; \
    float Tp00=fmaf(dt2,ht11,fmaf(2.f*dt,ht01,ht00))+qth; \
    float Tp01=fmaf(dt,ht11,ht01); \
    float Tp11=ht11+qdth; \
    float St=Tp00+Rt, ist=__builtin_amdgcn_rcpf(St); \
    float kt0=Tp00*ist, kt1=Tp01*ist; \
    ht00=Tp00-kt0*Tp00; ht01=Tp01-kt0*Tp01; ht11=Tp11-kt1*Tp01; \
    PRED_UPD(kx0,kx1,kt0,kt1,Z0,Z1,Z2) \
    facc += Sx*Sx*St + isx*fmaf(y0,y0,y1*y1) + ist*y2*y2; } }

#define READ6() \
    float4 v0=*(const float4*)&fb[4*((cb+0)^rx)]; \
    float4 v1=*(const float4*)&fb[4*((cb+1)^rx)]; \
    float4 v2=*(const float4*)&fb[4*((cb+2)^rx)]; \
    float4 v3=*(const float4*)&fb[4*((cb+3)^rx)]; \
    float4 v4=*(const float4*)&fb[4*((cb+4)^rx)]; \
    float4 v5=*(const float4*)&fb[4*((cb+5)^rx)]; \
    if (!inited && m0 == mst-1) { \
        s0=v0.x; s1=v0.y; s4=v0.z; \
        s2=(v0.w-v0.x)/dt; s3=(v1.x-v0.y)/dt; s5=(v1.y-v0.z)/dt; inited=true; }

    for (int f = 0; f < T_S; ++f) {
        if (f <= T_S-3)      asm volatile("s_waitcnt vmcnt(24)" ::: "memory");
        else if (f == T_S-2) asm volatile("s_waitcnt vmcnt(12)" ::: "memory");
        else                 asm volatile("s_waitcnt vmcnt(0)"  ::: "memory");
        __builtin_amdgcn_sched_barrier(0);
        __builtin_amdgcn_s_barrier();            // frame f visible to both waves
        __builtin_amdgcn_sched_barrier(0);

        const float* fb = &lds[(f % 3) * SLOT_F + lane * 96];
        if (exact) {
            for (int u = 0; u < 4; ++u) {
                int m0 = 32*f + 8*u, cb = 6*u;
                if (m0 + 8 <= mst-1 || m0 >= mown1) continue;
                READ6()
                XSTEP(0, v0.x,v0.y,v0.z)  XSTEP(1, v0.w,v1.x,v1.y)
                XSTEP(2, v1.z,v1.w,v2.x)  XSTEP(3, v2.y,v2.z,v2.w)
                XSTEP(4, v3.x,v3.y,v3.z)  XSTEP(5, v3.w,v4.x,v4.y)
                XSTEP(6, v4.z,v4.w,v5.x)  XSTEP(7, v5.y,v5.z,v5.w)
            }
        } else {
            for (int u = 0; u < 4; ++u) {
                int m0 = 32*f + 8*u, cb = 6*u;
                if (m0 + 8 <= mst-1 || m0 >= mown1) continue;
                READ6()
                TSTEP(0, v0.x,v0.y,v0.z)  TSTEP(1, v0.w,v1.x,v1.y)
                TSTEP(2, v1.z,v1.w,v2.x)  TSTEP(3, v2.y,v2.z,v2.w)
                TSTEP(4, v3.x,v3.y,v3.z)  TSTEP(5, v3.w,v4.x,v4.y)
                TSTEP(6, v4.z,v4.w,v5.x)  TSTEP(7, v5.y,v5.z,v5.w)
            }
        }
        __builtin_amdgcn_sched_barrier(0);
        __builtin_amdgcn_s_barrier();            // all reads of slot (f%3) done
        __builtin_amdgcn_sched_barrier(0);
        if (f + 3 < T_S) ISSUE(f + 3);           // overwrite slot (f%3)
    }
    asm volatile("s_waitcnt vmcnt(0)" ::: "memory");

#undef READ6
#undef XSTEP
#undef TSTEP
#undef PRED_UPD
#undef ISSUE

    float ft = exact ? facc : (float)nown * cdet + cisx * accP + cist * accT;
    double acc = (double)ft;
    for (int off = 32; off; off >>= 1) acc += __shfl_down(acc, off);
    if (lane == 0) wsum[wid] = acc;
    __syncthreads();
    if (tid == 0) part[B] = wsum[0] + wsum[1];
}

// ---- finalize: reduce 512 partials ----
__global__ void finalize_kernel(const double* __restrict__ part, float* __restrict__ out)
{
    const int tid = threadIdx.x;               // 512 threads
    double v = part[tid];
    for (int off = 32; off; off >>= 1) v += __shfl_down(v, off);
    __shared__ double wp[8];
    if ((tid & 63) == 0) wp[tid >> 6] = v;
    __syncthreads();
    if (tid == 0) {
        double t = 0.0;
        #pragma unroll
        for (int i = 0; i < 8; ++i) t += wp[i];
        out[0] = (float)(t / ((double)Bn * (double)NS));
    }
}

extern "C" void kernel_launch(void* const* d_in, const int* in_sizes, int n_in,
                              void* d_out, int out_size, void* d_ws, size_t ws_size,
                              hipStream_t stream)
{
    const float* params = (const float*)d_in[0];
    const float* meas = (const float*)d_in[1];
    double* part = (double*)d_ws;
    float* out = (float*)d_out;

    hipLaunchKernelGGL(ekf_main, dim3(NBLK), dim3(BT), 0, stream, params, meas, part);
    hipLaunchKernelGGL(finalize_kernel, dim3(1), dim3(512), 0, stream, part, out);
}